// Round 2
// baseline (127.323 us; speedup 1.0000x reference)
//
#include <hip/hip_runtime.h>

typedef __attribute__((ext_vector_type(8))) short short8;
typedef __attribute__((ext_vector_type(4))) short short4v;
typedef __attribute__((ext_vector_type(4))) float f32x4;

__device__ __forceinline__ float bf2f(short s) {
  union { unsigned u; float f; } cv;
  cv.u = ((unsigned)(unsigned short)s) << 16;
  return cv.f;
}
__device__ __forceinline__ short f2bf(float f) {
  union { float f; unsigned u; } cv;
  cv.f = f;
  unsigned r = (cv.u + 0x7fffu + ((cv.u >> 16) & 1u)) >> 16;
  return (short)(unsigned short)r;
}

#define MFMA16(a, b, c) __builtin_amdgcn_mfma_f32_16x16x32_bf16((a), (b), (c), 0, 0, 0)

// ---------------------------------------------------------------------------
// convert fp32 weight matrices -> bf16 workspace. 4 matrices x 32768 elems.
// ---------------------------------------------------------------------------
__global__ __launch_bounds__(256) void cvt_w(
    const float* __restrict__ s0, const float* __restrict__ s1,
    const float* __restrict__ s2, const float* __restrict__ s3,
    short* __restrict__ d)
{
  const float* srcs[4] = {s0, s1, s2, s3};
  const float* s = srcs[blockIdx.y];
  int i = (blockIdx.x * 256 + threadIdx.x) * 4;
  f32x4 v = *reinterpret_cast<const f32x4*>(s + i);
  short4v o;
  #pragma unroll
  for (int j = 0; j < 4; j++) o[j] = f2bf(v[j]);
  *reinterpret_cast<short4v*>(d + (size_t)blockIdx.y * 32768 + i) = o;
}

// ---------------------------------------------------------------------------
// conv1x1: out[b][p][o] = sum_c in[b][c][p] * w[o][c] + bias[o]
// in: fp32 [b][c][4096]; w: bf16 [o][256] (pre-converted); out: bf16 [b][p][o]
// M = pixels (64/block, 16/wave), N = 128 out-ch, K = 256 in steps of 32.
// ---------------------------------------------------------------------------
template <int NPROJ>
__global__ __launch_bounds__(256) void conv_proj(
    const float* __restrict__ in,
    const short* __restrict__ w0, const float* __restrict__ bias0,
    const short* __restrict__ w1, const float* __restrict__ bias1,
    short* __restrict__ out0, short* __restrict__ out1)
{
  __shared__ short in_t[64][40];            // [p][c], octet-XOR swizzled
  __shared__ short wt[NPROJ][128][40];      // [o][c], octet-XOR swizzled

  const int b = blockIdx.y;
  const int p0 = blockIdx.x * 64;
  const int tid = threadIdx.x;
  const int wave = tid >> 6, lane = tid & 63;
  const int lr = lane & 15, lg = lane >> 4;

  const short* wsrc[2] = {w0, w1};

  f32x4 acc[NPROJ][8];
  #pragma unroll
  for (int pj = 0; pj < NPROJ; pj++)
    #pragma unroll
    for (int n = 0; n < 8; n++) acc[pj][n] = (f32x4)0.0f;

  for (int kc = 0; kc < 256; kc += 32) {
    __syncthreads();
    {
      int c = tid >> 3;                 // 0..31
      int pg = (tid & 7) * 8;           // pixel group
      const float* src = in + ((size_t)(b * 256 + kc + c)) * 4096 + p0 + pg;
      f32x4 v0 = *reinterpret_cast<const f32x4*>(src);
      f32x4 v1 = *reinterpret_cast<const f32x4*>(src + 4);
      #pragma unroll
      for (int j = 0; j < 8; j++) {
        int p = pg + j;
        float fv = (j < 4) ? v0[j] : v1[j - 4];
        in_t[p][c ^ ((((p >> 3) & 3)) << 3)] = f2bf(fv);
      }
    }
    for (int idx = tid; idx < NPROJ * 128; idx += 256) {
      int pj = idx >> 7, o = idx & 127;
      const short8* src = reinterpret_cast<const short8*>(wsrc[pj] + (size_t)o * 256 + kc);
      int f = (o >> 3) & 3;
      #pragma unroll
      for (int g = 0; g < 4; g++)
        *reinterpret_cast<short8*>(&wt[pj][o][(g ^ f) * 8]) = src[g];
    }
    __syncthreads();

    int arow = wave * 16 + lr;
    short8 afrag = *reinterpret_cast<const short8*>(
        &in_t[arow][(lg ^ ((arow >> 3) & 3)) * 8]);
    #pragma unroll
    for (int pj = 0; pj < NPROJ; pj++) {
      #pragma unroll
      for (int n = 0; n < 8; n++) {
        int brow = n * 16 + lr;
        short8 bfrag = *reinterpret_cast<const short8*>(
            &wt[pj][brow][(lg ^ ((brow >> 3) & 3)) * 8]);
        acc[pj][n] = MFMA16(afrag, bfrag, acc[pj][n]);
      }
    }
  }

  const float* bsrc[2] = {bias0, bias1};
  short* osrc[2] = {out0, out1};
  #pragma unroll
  for (int pj = 0; pj < NPROJ; pj++) {
    #pragma unroll
    for (int n = 0; n < 8; n++) {
      int o = n * 16 + lr;
      float bv = bsrc[pj][o];
      #pragma unroll
      for (int r = 0; r < 4; r++) {
        int prow = p0 + wave * 16 + lg * 4 + r;
        osrc[pj][((size_t)b * 4096 + prow) * 128 + o] = f2bf(acc[pj][n][r] + bv);
      }
    }
  }
}

// ---------------------------------------------------------------------------
// maxpool 2x2: src bf16 [b][p=4096][128] -> dst bf16 [b][kp=1024][128]
// ---------------------------------------------------------------------------
__global__ __launch_bounds__(256) void pool_phi_k(const short* __restrict__ src,
                                                  short* __restrict__ dst)
{
  int b = blockIdx.y;
  int kp = blockIdx.x * 16 + (threadIdx.x >> 4);
  int o8 = (threadIdx.x & 15) * 8;
  int ph = kp >> 5, pw = kp & 31;
  size_t base = ((size_t)b * 4096 + ph * 128 + pw * 2) * 128 + o8;
  short8 v0 = *reinterpret_cast<const short8*>(src + base);
  short8 v1 = *reinterpret_cast<const short8*>(src + base + 128);
  short8 v2 = *reinterpret_cast<const short8*>(src + base + 64 * 128);
  short8 v3 = *reinterpret_cast<const short8*>(src + base + 65 * 128);
  short8 o;
  #pragma unroll
  for (int j = 0; j < 8; j++) {
    float m = fmaxf(fmaxf(bf2f(v0[j]), bf2f(v1[j])), fmaxf(bf2f(v2[j]), bf2f(v3[j])));
    o[j] = f2bf(m);
  }
  *reinterpret_cast<short8*>(dst + ((size_t)b * 1024 + kp) * 128 + o8) = o;
}

// ---------------------------------------------------------------------------
// maxpool 2x2 + transpose: src bf16 [b][p=4096][128] -> dst bf16 [b][128][kp=1024]
// ---------------------------------------------------------------------------
__global__ __launch_bounds__(256) void pool_g_t(const short* __restrict__ src,
                                                short* __restrict__ dst)
{
  __shared__ short s[32][136];
  int b = blockIdx.y;
  int kp0 = blockIdx.x * 32;
  int t = threadIdx.x;
  {
    int kpl = t >> 3;
    int o0 = (t & 7) * 16;
    int kp = kp0 + kpl;
    int ph = kp >> 5, pw = kp & 31;
    size_t base = ((size_t)b * 4096 + ph * 128 + pw * 2) * 128;
    #pragma unroll
    for (int h = 0; h < 2; h++) {
      int oo = o0 + h * 8;
      short8 v0 = *reinterpret_cast<const short8*>(src + base + oo);
      short8 v1 = *reinterpret_cast<const short8*>(src + base + 128 + oo);
      short8 v2 = *reinterpret_cast<const short8*>(src + base + 64 * 128 + oo);
      short8 v3 = *reinterpret_cast<const short8*>(src + base + 65 * 128 + oo);
      #pragma unroll
      for (int j = 0; j < 8; j++) {
        float m = fmaxf(fmaxf(bf2f(v0[j]), bf2f(v1[j])), fmaxf(bf2f(v2[j]), bf2f(v3[j])));
        s[kpl][oo + j] = f2bf(m);
      }
    }
  }
  __syncthreads();
  {
    int o = t >> 1;
    int k0 = (t & 1) * 16;
    short8 v0, v1;
    #pragma unroll
    for (int j = 0; j < 8; j++) { v0[j] = s[k0 + j][o]; v1[j] = s[k0 + 8 + j][o]; }
    *reinterpret_cast<short8*>(dst + ((size_t)b * 128 + o) * 1024 + kp0 + k0) = v0;
    *reinterpret_cast<short8*>(dst + ((size_t)b * 128 + o) * 1024 + kp0 + k0 + 8) = v1;
  }
}

// ---------------------------------------------------------------------------
// flash attention: per (b, 64-q tile). theta [b][4096][128], phi [b][1024][128],
// g [b][128][1024] (all bf16) -> y bf16 [b][4096][128]. fp32 online softmax.
// ---------------------------------------------------------------------------
__global__ __launch_bounds__(256) void attn(
    const short* __restrict__ theta, const short* __restrict__ phi,
    const short* __restrict__ g, short* __restrict__ y)
{
  __shared__ short theta_s[64][136];
  __shared__ short phi_s[64][136];
  __shared__ short g_s[128][72];
  __shared__ short p_s[64][72];

  const int b = blockIdx.y;
  const int q0 = blockIdx.x * 64;
  const int tid = threadIdx.x;
  const int wave = tid >> 6, lane = tid & 63;
  const int lr = lane & 15, lg = lane >> 4;

  {
    int r = tid >> 2, c0 = (tid & 3) * 32;
    const short8* src = reinterpret_cast<const short8*>(
        theta + ((size_t)b * 4096 + q0 + r) * 128 + c0);
    short8* dstv = reinterpret_cast<short8*>(&theta_s[r][c0]);
    #pragma unroll
    for (int j = 0; j < 4; j++) dstv[j] = src[j];
  }

  float mrun[4], lrun[4];
  #pragma unroll
  for (int r = 0; r < 4; r++) { mrun[r] = -1e30f; lrun[r] = 0.0f; }
  f32x4 acc[8];
  #pragma unroll
  for (int n = 0; n < 8; n++) acc[n] = (f32x4)0.0f;

  for (int k0 = 0; k0 < 1024; k0 += 64) {
    __syncthreads();
    {
      int r = tid >> 2, c0 = (tid & 3) * 32;
      const short8* src = reinterpret_cast<const short8*>(
          phi + ((size_t)b * 1024 + k0 + r) * 128 + c0);
      short8* dstv = reinterpret_cast<short8*>(&phi_s[r][c0]);
      #pragma unroll
      for (int j = 0; j < 4; j++) dstv[j] = src[j];
      int o = tid >> 1, h0 = (tid & 1) * 32;
      const short8* sg = reinterpret_cast<const short8*>(
          g + ((size_t)b * 128 + o) * 1024 + k0 + h0);
      short8* dg = reinterpret_cast<short8*>(&g_s[o][h0]);
      #pragma unroll
      for (int j = 0; j < 4; j++) dg[j] = sg[j];
    }
    __syncthreads();

    // f = theta . phi^T  (16 q-rows per wave x 64 kv-cols)
    f32x4 facc[4];
    #pragma unroll
    for (int n = 0; n < 4; n++) facc[n] = (f32x4)0.0f;
    #pragma unroll
    for (int kk = 0; kk < 4; kk++) {
      short8 afrag = *reinterpret_cast<const short8*>(&theta_s[wave * 16 + lr][kk * 32 + lg * 8]);
      #pragma unroll
      for (int n = 0; n < 4; n++) {
        short8 bfrag = *reinterpret_cast<const short8*>(&phi_s[n * 16 + lr][kk * 32 + lg * 8]);
        facc[n] = MFMA16(afrag, bfrag, facc[n]);
      }
    }

    // online softmax (row = lg*4 + r within wave tile)
    #pragma unroll
    for (int r = 0; r < 4; r++) {
      float mx = fmaxf(fmaxf(facc[0][r], facc[1][r]), fmaxf(facc[2][r], facc[3][r]));
      #pragma unroll
      for (int off = 8; off >= 1; off >>= 1) mx = fmaxf(mx, __shfl_xor(mx, off));
      float mo = mrun[r];
      float mn = fmaxf(mo, mx);
      mrun[r] = mn;
      float sc = __expf(mo - mn);
      float rs = 0.0f;
      int prow = wave * 16 + lg * 4 + r;
      #pragma unroll
      for (int n = 0; n < 4; n++) {
        float pv = __expf(facc[n][r] - mn);
        rs += pv;
        p_s[prow][n * 16 + lr] = f2bf(pv);
      }
      #pragma unroll
      for (int off = 8; off >= 1; off >>= 1) rs += __shfl_xor(rs, off);
      lrun[r] = lrun[r] * sc + rs;
      #pragma unroll
      for (int n = 0; n < 8; n++) acc[n][r] *= sc;
    }
    __syncthreads();

    // y += P . g^T
    #pragma unroll
    for (int kk = 0; kk < 2; kk++) {
      short8 pa = *reinterpret_cast<const short8*>(&p_s[wave * 16 + lr][kk * 32 + lg * 8]);
      #pragma unroll
      for (int n = 0; n < 8; n++) {
        short8 gb = *reinterpret_cast<const short8*>(&g_s[n * 16 + lr][kk * 32 + lg * 8]);
        acc[n] = MFMA16(pa, gb, acc[n]);
      }
    }
  }

  #pragma unroll
  for (int n = 0; n < 8; n++) {
    #pragma unroll
    for (int r = 0; r < 4; r++) {
      int q = q0 + wave * 16 + lg * 4 + r;
      y[((size_t)b * 4096 + q) * 128 + n * 16 + lr] = f2bf(acc[n][r] / lrun[r]);
    }
  }
}

// ---------------------------------------------------------------------------
// wy = w_w . y (per pixel) + bias, BN (eval), + x  -> out fp32 [b][256][4096]
// y: bf16 [b][4096][128]; ww: bf16 [256][128] (pre-converted); rest fp32.
// M = 256 co (64/wave), N = 64 q, K = 128 ci
// ---------------------------------------------------------------------------
__global__ __launch_bounds__(256) void wconv_bn(
    const short* __restrict__ y, const short* __restrict__ ww,
    const float* __restrict__ wb,
    const float* __restrict__ gamma, const float* __restrict__ beta,
    const float* __restrict__ mean, const float* __restrict__ var,
    const float* __restrict__ x, float* __restrict__ out)
{
  __shared__ short y_s[64][136];
  __shared__ float sc_s[256];
  __shared__ float sh_s[256];

  const int b = blockIdx.y;
  const int q0 = blockIdx.x * 64;
  const int tid = threadIdx.x;
  const int wave = tid >> 6, lane = tid & 63;
  const int lr = lane & 15, lg = lane >> 4;

  {
    int r = tid >> 2, c0 = (tid & 3) * 32;
    const short8* src = reinterpret_cast<const short8*>(
        y + ((size_t)b * 4096 + q0 + r) * 128 + c0);
    short8* dstv = reinterpret_cast<short8*>(&y_s[r][c0]);
    #pragma unroll
    for (int j = 0; j < 4; j++) dstv[j] = src[j];
    float s = gamma[tid] * rsqrtf(var[tid] + 1e-5f);
    sc_s[tid] = s;
    sh_s[tid] = (wb[tid] - mean[tid]) * s + beta[tid];
  }
  __syncthreads();

  f32x4 acc[4][4];
  #pragma unroll
  for (int m = 0; m < 4; m++)
    #pragma unroll
    for (int n = 0; n < 4; n++) acc[m][n] = (f32x4)0.0f;

  #pragma unroll
  for (int kk = 0; kk < 4; kk++) {
    short8 af[4], bfr[4];
    #pragma unroll
    for (int m = 0; m < 4; m++)
      af[m] = *reinterpret_cast<const short8*>(
          ww + (size_t)(wave * 64 + m * 16 + lr) * 128 + kk * 32 + lg * 8);
    #pragma unroll
    for (int n = 0; n < 4; n++)
      bfr[n] = *reinterpret_cast<const short8*>(&y_s[n * 16 + lr][kk * 32 + lg * 8]);
    #pragma unroll
    for (int m = 0; m < 4; m++)
      #pragma unroll
      for (int n = 0; n < 4; n++)
        acc[m][n] = MFMA16(af[m], bfr[n], acc[m][n]);
  }

  #pragma unroll
  for (int m = 0; m < 4; m++) {
    #pragma unroll
    for (int n = 0; n < 4; n++) {
      #pragma unroll
      for (int r = 0; r < 4; r++) {
        int co = wave * 64 + m * 16 + lg * 4 + r;
        int q = q0 + n * 16 + lr;
        size_t oidx = ((size_t)b * 256 + co) * 4096 + q;
        float v = acc[m][n][r] * sc_s[co] + sh_s[co];
        out[oidx] = v + x[oidx];
      }
    }
  }
}

// ---------------------------------------------------------------------------
extern "C" void kernel_launch(void* const* d_in, const int* in_sizes, int n_in,
                              void* d_out, int out_size, void* d_ws, size_t ws_size,
                              hipStream_t stream)
{
  const float* x    = (const float*)d_in[0];
  const float* nb   = (const float*)d_in[1];
  const float* g_w  = (const float*)d_in[2];
  const float* g_b  = (const float*)d_in[3];
  const float* th_w = (const float*)d_in[4];
  const float* th_b = (const float*)d_in[5];
  const float* ph_w = (const float*)d_in[6];
  const float* ph_b = (const float*)d_in[7];
  const float* w_w  = (const float*)d_in[8];
  const float* w_b  = (const float*)d_in[9];
  const float* gam  = (const float*)d_in[10];
  const float* bet  = (const float*)d_in[11];
  const float* mu   = (const float*)d_in[12];
  const float* var  = (const float*)d_in[13];
  float* out = (float*)d_out;

  char* ws = (char*)d_ws;
  short* theta_full = (short*)(ws);                        // 8 MB  [b][4096][128]
  short* phi_full   = (short*)(ws + (size_t)(8u << 20));   // 8 MB  [b][4096][128]
  short* g_full     = (short*)(ws + (size_t)(16u << 20));  // 8 MB  [b][4096][128]
  short* phi_kc     = (short*)(ws + (size_t)(24u << 20));  // 2 MB  [b][1024][128]
  short* g_ck       = (short*)(ws + (size_t)(26u << 20));  // 2 MB  [b][128][1024]
  short* yb         = (short*)(ws + (size_t)(28u << 20));  // 8 MB  [b][4096][128]
  short* wts        = (short*)(ws + (size_t)(36u << 20));  // 256KB: th, ph, g, w
  short* th_wb = wts;
  short* ph_wb = wts + 32768;
  short* g_wb  = wts + 2 * 32768;
  short* w_wb  = wts + 3 * 32768;

  cvt_w<<<dim3(32, 4), 256, 0, stream>>>(th_w, ph_w, g_w, w_w, wts);
  conv_proj<2><<<dim3(64, 8), 256, 0, stream>>>(nb, th_wb, th_b, ph_wb, ph_b,
                                                theta_full, phi_full);
  conv_proj<1><<<dim3(64, 8), 256, 0, stream>>>(x, g_wb, g_b, nullptr, nullptr,
                                                g_full, nullptr);
  pool_phi_k<<<dim3(64, 8), 256, 0, stream>>>(phi_full, phi_kc);
  pool_g_t<<<dim3(32, 8), 256, 0, stream>>>(g_full, g_ck);
  attn<<<dim3(64, 8), 256, 0, stream>>>(theta_full, phi_kc, g_ck, yb);
  wconv_bn<<<dim3(64, 8), 256, 0, stream>>>(yb, w_wb, w_b, gam, bet, mu, var, x, out);
}